// Round 9
// baseline (207.727 us; speedup 1.0000x reference)
//
#include <hip/hip_runtime.h>
#include <math.h>

#define N_NODES 20000
#define N_EDGES 160000
#define EPAD    160040     // E + 40 (aligned-window slack), even

#define PI_F 3.14159265358979323846f
#define LN2_F 0.69314718055994530942f

#define W1PK 43008         // 21 ksteps * 4 colfrags * 64 lanes * 8 (ushort units)
#define W23PK 4096         // 2 ksteps  * 4 * 64 * 8
#define WPK_LAYER 51200    // per-layer packed weights (ushort units)
#define XROW 680           // LDS X row stride in u16 (1360 B, 16B-aligned)

typedef short short8v __attribute__((ext_vector_type(8)));
typedef float f32x4 __attribute__((ext_vector_type(4)));
typedef unsigned short u16;

__device__ __forceinline__ float sspf(float x) {
    return fmaxf(x, 0.0f) + log1pf(expf(-fabsf(x))) - LN2_F;
}
// round-to-nearest-even f32 -> bf16
__device__ __forceinline__ u16 f2bf(float f) {
    unsigned int u = __float_as_uint(f);
    return (u16)((u + 0x7fffu + ((u >> 16) & 1u)) >> 16);
}
__device__ __forceinline__ unsigned int pk2(float a, float b) {
    return (unsigned int)f2bf(a) | ((unsigned int)f2bf(b) << 16);
}

// ---------------------------------------------------------------------------
// WT[nb][e] = bf16( sw[e] * sqrt(2/5)*sin((n+1) pi r/5)/r * bo[e][b] ),
// nb = n*5+b in 0..39; e in [0, EPAD) with e >= E zeroed. Row-major [48][EPAD]
// (rows 40..47 never written -> only ever multiply into discarded C rows).
// ---------------------------------------------------------------------------
__global__ __launch_bounds__(256) void edge_wt_kernel(
    const float* __restrict__ dist,
    const float* __restrict__ sw,
    const float* __restrict__ bo,
    u16* __restrict__ WT)
{
    int nb = blockIdx.y;                       // 0..39
    int idx = blockIdx.x * 256 + threadIdx.x;  // pair index
    int e2 = idx * 2;
    if (e2 >= EPAD) return;
    int n = nb / 5, b = nb - n * 5;
    float fn = (float)(n + 1) * PI_F * 0.2f;
    float v0 = 0.f, v1 = 0.f;
    if (e2 < N_EDGES) {
        float r = dist[e2];
        v0 = sqrtf(0.4f) / r * sw[e2] * sinf(fn * r) * bo[(size_t)e2 * 5 + b];
    }
    if (e2 + 1 < N_EDGES) {
        float r = dist[e2 + 1];
        v1 = sqrtf(0.4f) / r * sw[e2 + 1] * sinf(fn * r) * bo[(size_t)(e2 + 1) * 5 + b];
    }
    *reinterpret_cast<unsigned int*>(WT + (size_t)nb * EPAD + e2) = pk2(v0, v1);
}

// ---------------------------------------------------------------------------
// CSR offsets from sorted edge_src
// ---------------------------------------------------------------------------
__global__ __launch_bounds__(256) void row_start_kernel(
    const int* __restrict__ src, int* __restrict__ row)
{
    int i = blockIdx.x * blockDim.x + threadIdx.x;
    if (i > N_NODES) return;
    int lo = 0, hi = N_EDGES;
    while (lo < hi) {
        int mid = (lo + hi) >> 1;
        if (src[mid] < i) lo = mid + 1; else hi = mid;
    }
    row[i] = lo;
}

// ---------------------------------------------------------------------------
// xi = W_species[species]
// ---------------------------------------------------------------------------
__global__ __launch_bounds__(256) void xi_init_kernel(
    const int* __restrict__ species,
    const float* __restrict__ Wsp,
    float* __restrict__ xi)
{
    int idx = blockIdx.x * blockDim.x + threadIdx.x;
    if (idx >= N_NODES * 16) return;
    int node = idx >> 4;
    int c4 = idx & 15;
    int sp = species[node];
    reinterpret_cast<float4*>(xi)[idx] =
        reinterpret_cast<const float4*>(Wsp + (size_t)sp * 64)[c4];
}

// ---------------------------------------------------------------------------
// Pack FC weights -> bf16 B-fragment layout for mfma_f32_16x16x32_bf16.
// NEW X layout: feature f' = nb*16 + s  (nb = n*5+b)  ->  orig W1 row
// n*80 + s*5 + b.  Rows 640..655 = si (unchanged); k >= 656 zero.
// ---------------------------------------------------------------------------
__global__ __launch_bounds__(256) void pack_w_kernel(
    const float* __restrict__ fcW1,
    const float* __restrict__ fcW2,
    const float* __restrict__ fcW3,
    u16* __restrict__ Wpk)
{
    int idx = blockIdx.x * 256 + threadIdx.x;
    if (idx >= 3 * WPK_LAYER) return;
    int layer = idx / WPK_LAYER;
    int r = idx - layer * WPK_LAYER;
    float val = 0.0f;
    if (r < W1PK) {
        int e = r;
        int j = e & 7, lane = (e >> 3) & 63, c16 = (e >> 9) & 3, ks = e >> 11;
        int k = ks * 32 + (lane >> 4) * 8 + j;
        int colm = c16 * 16 + (lane & 15);
        if (k < 640) {
            int nbv = k >> 4, ss = k & 15;
            int nn = nbv / 5, bb = nbv - nn * 5;
            val = fcW1[(size_t)layer * 656 * 64 + (size_t)(nn * 80 + ss * 5 + bb) * 64 + colm];
        } else if (k < 656) {
            val = fcW1[(size_t)layer * 656 * 64 + (size_t)k * 64 + colm];
        }
    } else {
        bool is2 = (r < W1PK + W23PK);
        const float* W = is2 ? fcW2 : fcW3;
        int e = is2 ? (r - W1PK) : (r - W1PK - W23PK);
        int j = e & 7, lane = (e >> 3) & 63, c16 = (e >> 9) & 3, ks = e >> 11;
        int k = ks * 32 + (lane >> 4) * 8 + j;
        int colm = c16 * 16 + (lane & 15);
        val = W[(size_t)layer * 64 * 64 + (size_t)k * 64 + colm];
    }
    Wpk[(size_t)layer * WPK_LAYER + r] = f2bf(val);
}

// ---------------------------------------------------------------------------
// h = xi @ Wl[l] + bl[l]   (N x 32).  float4 stores.
// ---------------------------------------------------------------------------
__global__ __launch_bounds__(256) void h_kernel(
    const float* __restrict__ xi,
    const float* __restrict__ Wl,
    const float* __restrict__ bl,
    float* __restrict__ h)
{
    __shared__ float xs[32 * 64];
    __shared__ float ws[64 * 32];
    int tid = threadIdx.x;
    int nb = blockIdx.x * 32;

    const float4* xsrc = reinterpret_cast<const float4*>(xi + (size_t)nb * 64);
    float4* xd = reinterpret_cast<float4*>(xs);
    #pragma unroll
    for (int i = 0; i < 2; ++i) xd[tid + i * 256] = xsrc[tid + i * 256];
    const float4* wsrc = reinterpret_cast<const float4*>(Wl);
    float4* wd = reinterpret_cast<float4*>(ws);
    #pragma unroll
    for (int i = 0; i < 2; ++i) wd[tid + i * 256] = wsrc[tid + i * 256];
    __syncthreads();

    int c4g = tid & 7;
    int nrow = tid >> 3;
    float4 acc = *reinterpret_cast<const float4*>(bl + c4g * 4);
    const float* xr = xs + nrow * 64;
    #pragma unroll 8
    for (int j = 0; j < 64; ++j) {
        float xv = xr[j];
        float4 wv = *reinterpret_cast<const float4*>(ws + j * 32 + c4g * 4);
        acc.x = fmaf(xv, wv.x, acc.x);
        acc.y = fmaf(xv, wv.y, acc.y);
        acc.z = fmaf(xv, wv.z, acc.z);
        acc.w = fmaf(xv, wv.w, acc.w);
    }
    *reinterpret_cast<float4*>(h + (size_t)(nb + nrow) * 32 + c4g * 4) = acc;
}

// ---------------------------------------------------------------------------
// FUSED agg + FC chain. Block = 256 thr = 4 waves; 16 nodes per block.
// Phase A (v3, MFMA): per node, agg[nb][s] = (WT[48][deg]) @ (mi[deg][16])
//   as 3x mfma_f32_16x16x32_bf16 over a K=32 window starting at e0&~7
//   (16B-aligned A loads); B = mi gathered to registers, masked to
//   [e0, e1). C rows 0..39 -> Xs (f' = nb*16+s); rows 40..47 discarded.
// Phase B: MFMA FC1(K=672)/FC2/FC3 + xi residual (unchanged).
// ---------------------------------------------------------------------------
__global__ __launch_bounds__(256) void agg_fc_kernel(
    const u16* __restrict__ WT,             // [48][EPAD] bf16
    const int* __restrict__ row,
    const int* __restrict__ dst,
    const float* __restrict__ h,            // N x 32
    const u16* __restrict__ Wpk,            // layer's packed weights
    const float* __restrict__ b1,
    const float* __restrict__ b2,
    const float* __restrict__ b3,
    float* __restrict__ xi)
{
    __shared__ __align__(16) u16 Xs[16][XROW];   // 21760 B
    __shared__ __align__(16) u16 Y1[16 * 72];    //  2304 B
    __shared__ __align__(16) u16 Y2[16 * 72];    //  2304 B
    __shared__ __align__(16) float Yo[16 * 68];  //  4352 B

    int tid = threadIdx.x;
    int wv = tid >> 6;
    int lane = tid & 63;
    int s = lane & 15;      // col (s feature) / A row within tile
    int kg = lane >> 4;     // k-group 0..3
    int n0 = blockIdx.x * 16;
    int base = n0 + (wv << 2);

    // ---- si staging + zero pad (lane t=kg covers the wave's 4 nodes) ----
    {
        int t = kg;
        u16* xr = &Xs[(wv << 2) + t][0];
        xr[640 + s] = f2bf(h[(size_t)(base + t) * 32 + s]);
        xr[656 + s] = 0;
    }

    // ======== Phase A: MFMA aggregation, 4 nodes per wave ========
    for (int t = 0; t < 4; ++t) {
        int node = base + t;
        int e0 = row[node], e1 = row[node + 1];
        int e0a = e0 & ~7;                       // 16B-aligned window start
        int nks = (e1 - e0a + 31) >> 5;          // K tiles of 32

        f32x4 c0 = {0.f, 0.f, 0.f, 0.f};
        f32x4 c1 = {0.f, 0.f, 0.f, 0.f};
        f32x4 c2 = {0.f, 0.f, 0.f, 0.f};

        for (int kc = 0; kc < nks; ++kc) {
            int eb = e0a + kc * 32 + kg * 8;
            // ---- B fragment: mi for 8 edges, masked to [e0, e1) ----
            float m[8];
            #pragma unroll
            for (int j = 0; j < 8; ++j) {
                int e = eb + j;
                int ec = e < (N_EDGES - 1) ? e : (N_EDGES - 1);
                int d = dst[ec];
                float mv = h[(size_t)d * 32 + 16 + s];
                m[j] = (e >= e0 && e < e1) ? mv : 0.0f;
            }
            uint4 bu = make_uint4(pk2(m[0], m[1]), pk2(m[2], m[3]),
                                  pk2(m[4], m[5]), pk2(m[6], m[7]));
            short8v bfrag = *reinterpret_cast<short8v*>(&bu);
            // ---- A fragments: WT rows (16r + s), 16B-aligned loads ----
            const u16* ap = WT + (size_t)s * EPAD + eb;
            short8v a0 = *reinterpret_cast<const short8v*>(ap);
            short8v a1 = *reinterpret_cast<const short8v*>(ap + (size_t)16 * EPAD);
            short8v a2 = *reinterpret_cast<const short8v*>(ap + (size_t)32 * EPAD);
            c0 = __builtin_amdgcn_mfma_f32_16x16x32_bf16(a0, bfrag, c0, 0, 0, 0);
            c1 = __builtin_amdgcn_mfma_f32_16x16x32_bf16(a1, bfrag, c1, 0, 0, 0);
            c2 = __builtin_amdgcn_mfma_f32_16x16x32_bf16(a2, bfrag, c2, 0, 0, 0);
        }

        // ---- write C rows 0..39 into Xs[node] at f' = nb*16 + s ----
        u16* xr = &Xs[(wv << 2) + t][0];
        #pragma unroll
        for (int q = 0; q < 4; ++q) {
            xr[(kg * 4 + q) * 16 + s]      = f2bf(c0[q]);
            xr[(16 + kg * 4 + q) * 16 + s] = f2bf(c1[q]);
        }
        if (kg < 2) {
            #pragma unroll
            for (int q = 0; q < 4; ++q)
                xr[(32 + kg * 4 + q) * 16 + s] = f2bf(c2[q]);
        }
    }
    __syncthreads();

    // ======== Phase B: MFMA FC chain ========
    int w = wv;
    int l = lane;
    int lrow = l & 15;
    int lk = l >> 4;
    int col = w * 16 + lrow;

    const u16* Wpk1 = Wpk;
    const u16* Wpk2 = Wpk + W1PK;
    const u16* Wpk3 = Wpk + W1PK + W23PK;

    // ---- FC1: K = 672 (cols 656..671 zero x zero-packed W) ----
    f32x4 acc;
    {
        float bv = b1[col];
        acc[0] = bv; acc[1] = bv; acc[2] = bv; acc[3] = bv;
    }
    const u16* wp = Wpk1 + ((size_t)w * 64 + l) * 8;
    #pragma unroll
    for (int ks = 0; ks < 21; ++ks) {
        short8v a = *reinterpret_cast<const short8v*>(&Xs[lrow][ks * 32 + lk * 8]);
        short8v b = *reinterpret_cast<const short8v*>(wp + (size_t)ks * 2048);
        acc = __builtin_amdgcn_mfma_f32_16x16x32_bf16(a, b, acc, 0, 0, 0);
    }
    #pragma unroll
    for (int q = 0; q < 4; ++q)
        Y1[(lk * 4 + q) * 72 + col] = f2bf(sspf(acc[q]));
    __syncthreads();

    // ---- FC2: K = 64 ----
    {
        float bv = b2[col];
        acc[0] = bv; acc[1] = bv; acc[2] = bv; acc[3] = bv;
    }
    #pragma unroll
    for (int ks = 0; ks < 2; ++ks) {
        short8v a = *reinterpret_cast<const short8v*>(&Y1[lrow * 72 + ks * 32 + lk * 8]);
        short8v b = *reinterpret_cast<const short8v*>(Wpk2 + ((size_t)(ks * 4 + w) * 64 + l) * 8);
        acc = __builtin_amdgcn_mfma_f32_16x16x32_bf16(a, b, acc, 0, 0, 0);
    }
    #pragma unroll
    for (int q = 0; q < 4; ++q)
        Y2[(lk * 4 + q) * 72 + col] = f2bf(sspf(acc[q]));
    __syncthreads();

    // ---- FC3: K = 64 ----
    {
        float bv = b3[col];
        acc[0] = bv; acc[1] = bv; acc[2] = bv; acc[3] = bv;
    }
    #pragma unroll
    for (int ks = 0; ks < 2; ++ks) {
        short8v a = *reinterpret_cast<const short8v*>(&Y2[lrow * 72 + ks * 32 + lk * 8]);
        short8v b = *reinterpret_cast<const short8v*>(Wpk3 + ((size_t)(ks * 4 + w) * 64 + l) * 8);
        acc = __builtin_amdgcn_mfma_f32_16x16x32_bf16(a, b, acc, 0, 0, 0);
    }
    #pragma unroll
    for (int q = 0; q < 4; ++q)
        Yo[(lk * 4 + q) * 68 + col] = acc[q];
    __syncthreads();

    // ---- residual update, float4 per lane ----
    {
        int rr = tid >> 4;
        int cc = tid & 15;
        float4 dv = *reinterpret_cast<const float4*>(Yo + rr * 68 + cc * 4);
        float4* xpn = reinterpret_cast<float4*>(xi + (size_t)(n0 + rr) * 64 + cc * 4);
        float4 o = *xpn;
        o.x += dv.x; o.y += dv.y; o.z += dv.z; o.w += dv.w;
        *xpn = o;
    }
}

// ---------------------------------------------------------------------------
extern "C" void kernel_launch(void* const* d_in, const int* in_sizes, int n_in,
                              void* d_out, int out_size, void* d_ws, size_t ws_size,
                              hipStream_t stream) {
    const int*   species = (const int*)d_in[0];
    const int*   esrc    = (const int*)d_in[1];
    const int*   edst    = (const int*)d_in[2];
    const float* dist    = (const float*)d_in[3];
    const float* sw      = (const float*)d_in[4];
    const float* bo      = (const float*)d_in[5];
    const float* Wsp     = (const float*)d_in[6];
    const float* Wl      = (const float*)d_in[7];
    const float* bl      = (const float*)d_in[8];
    const float* fcW1    = (const float*)d_in[9];
    const float* fcb1    = (const float*)d_in[10];
    const float* fcW2    = (const float*)d_in[11];
    const float* fcb2    = (const float*)d_in[12];
    const float* fcW3    = (const float*)d_in[13];
    const float* fcb3    = (const float*)d_in[14];
    float* xi = (float*)d_out;

    char* ws = (char*)d_ws;
    u16*   WT   = (u16*)ws;                     // 48*EPAD*2 = 15,363,840 B
    int*   rowp = (int*)(ws + 15363840);        //     80,128 B
    float* h    = (float*)(ws + 15443968);      //  2,560,000 B
    u16*   Wpk  = (u16*)(ws + 18003968);        //    307,200 B

    hipLaunchKernelGGL(edge_wt_kernel, dim3(313, 40), dim3(256), 0, stream,
                       dist, sw, bo, WT);
    hipLaunchKernelGGL(row_start_kernel, dim3(79), dim3(256), 0, stream,
                       esrc, rowp);
    hipLaunchKernelGGL(xi_init_kernel, dim3(1250), dim3(256), 0, stream,
                       species, Wsp, xi);
    hipLaunchKernelGGL(pack_w_kernel, dim3(600), dim3(256), 0, stream,
                       fcW1, fcW2, fcW3, Wpk);

    for (int l = 0; l < 3; ++l) {
        hipLaunchKernelGGL(h_kernel, dim3(625), dim3(256), 0, stream,
                           xi, Wl + (size_t)l * 64 * 32, bl + (size_t)l * 32, h);
        hipLaunchKernelGGL(agg_fc_kernel, dim3(1250), dim3(256), 0, stream,
                           WT, rowp, edst, h,
                           Wpk + (size_t)l * WPK_LAYER,
                           fcb1 + (size_t)l * 64, fcb2 + (size_t)l * 64,
                           fcb3 + (size_t)l * 64, xi);
    }
}

// Round 11
// 141.123 us; speedup vs baseline: 1.4720x; 1.4720x over previous
//
#include <hip/hip_runtime.h>
#include <math.h>

#define N_NODES 20000
#define N_EDGES 160000
#define EPAD    160256     // multiple of 256 (gather blocks) with >=32 slack

#define PI_F 3.14159265358979323846f
#define LN2_F 0.69314718055994530942f

#define W1PK 43008         // 21 ksteps * 4 colfrags * 64 lanes * 8 (ushort units)
#define W23PK 4096         // 2 ksteps  * 4 * 64 * 8
#define WPK_LAYER 51200    // per-layer packed weights (ushort units)
#define XROW 680           // LDS X row stride in u16 (1360 B, 16B-aligned)

typedef short short8v __attribute__((ext_vector_type(8)));
typedef float f32x4 __attribute__((ext_vector_type(4)));
typedef unsigned short u16;
typedef unsigned long long ull;

__device__ __forceinline__ float sspf(float x) {
    return fmaxf(x, 0.0f) + log1pf(expf(-fabsf(x))) - LN2_F;
}
// round-to-nearest-even f32 -> bf16
__device__ __forceinline__ u16 f2bf(float f) {
    unsigned int u = __float_as_uint(f);
    return (u16)((u + 0x7fffu + ((u >> 16) & 1u)) >> 16);
}
__device__ __forceinline__ unsigned int pk2(float a, float b) {
    return (unsigned int)f2bf(a) | ((unsigned int)f2bf(b) << 16);
}
// mask of 4 u16 slots: slots j >= t are 0xFFFF (t clamped to [0,4])
__device__ __forceinline__ ull mge(int t) {
    t = t < 0 ? 0 : (t > 4 ? 4 : t);
    return t == 4 ? 0ULL : (~0ULL << (t * 16));
}

// ---------------------------------------------------------------------------
// WT[nb][e] = bf16( sw*sqrt(2/5)*sin((n+1) pi r/5)/r * bo[e][b] ), [48][EPAD]
// rows 40..47 never written (feed discarded C rows); e >= E zeroed.
// ---------------------------------------------------------------------------
__global__ __launch_bounds__(256) void edge_wt_kernel(
    const float* __restrict__ dist,
    const float* __restrict__ sw,
    const float* __restrict__ bo,
    u16* __restrict__ WT)
{
    int nb = blockIdx.y;                       // 0..39
    int idx = blockIdx.x * 256 + threadIdx.x;  // pair index; grid.x = EPAD/512
    int e2 = idx * 2;
    if (e2 >= EPAD) return;
    int n = nb / 5, b = nb - n * 5;
    float fn = (float)(n + 1) * PI_F * 0.2f;
    float v0 = 0.f, v1 = 0.f;
    if (e2 < N_EDGES) {
        float r = dist[e2];
        v0 = sqrtf(0.4f) / r * sw[e2] * sinf(fn * r) * bo[(size_t)e2 * 5 + b];
    }
    if (e2 + 1 < N_EDGES) {
        float r = dist[e2 + 1];
        v1 = sqrtf(0.4f) / r * sw[e2 + 1] * sinf(fn * r) * bo[(size_t)(e2 + 1) * 5 + b];
    }
    *reinterpret_cast<unsigned int*>(WT + (size_t)nb * EPAD + e2) = pk2(v0, v1);
}

// ---------------------------------------------------------------------------
// CSR offsets from sorted edge_src
// ---------------------------------------------------------------------------
__global__ __launch_bounds__(256) void row_start_kernel(
    const int* __restrict__ src, int* __restrict__ row)
{
    int i = blockIdx.x * blockDim.x + threadIdx.x;
    if (i > N_NODES) return;
    int lo = 0, hi = N_EDGES;
    while (lo < hi) {
        int mid = (lo + hi) >> 1;
        if (src[mid] < i) lo = mid + 1; else hi = mid;
    }
    row[i] = lo;
}

// ---------------------------------------------------------------------------
// xi = W_species[species]
// ---------------------------------------------------------------------------
__global__ __launch_bounds__(256) void xi_init_kernel(
    const int* __restrict__ species,
    const float* __restrict__ Wsp,
    float* __restrict__ xi)
{
    int idx = blockIdx.x * blockDim.x + threadIdx.x;
    if (idx >= N_NODES * 16) return;
    int node = idx >> 4;
    int c4 = idx & 15;
    int sp = species[node];
    reinterpret_cast<float4*>(xi)[idx] =
        reinterpret_cast<const float4*>(Wsp + (size_t)sp * 64)[c4];
}

// ---------------------------------------------------------------------------
// Pack FC weights -> bf16 B-fragment layout. X feature f' = nb*16 + s.
// ---------------------------------------------------------------------------
__global__ __launch_bounds__(256) void pack_w_kernel(
    const float* __restrict__ fcW1,
    const float* __restrict__ fcW2,
    const float* __restrict__ fcW3,
    u16* __restrict__ Wpk)
{
    int idx = blockIdx.x * 256 + threadIdx.x;
    if (idx >= 3 * WPK_LAYER) return;
    int layer = idx / WPK_LAYER;
    int r = idx - layer * WPK_LAYER;
    float val = 0.0f;
    if (r < W1PK) {
        int e = r;
        int j = e & 7, lane = (e >> 3) & 63, c16 = (e >> 9) & 3, ks = e >> 11;
        int k = ks * 32 + (lane >> 4) * 8 + j;
        int colm = c16 * 16 + (lane & 15);
        if (k < 640) {
            int nbv = k >> 4, ss = k & 15;
            int nn = nbv / 5, bb = nbv - nn * 5;
            val = fcW1[(size_t)layer * 656 * 64 + (size_t)(nn * 80 + ss * 5 + bb) * 64 + colm];
        } else if (k < 656) {
            val = fcW1[(size_t)layer * 656 * 64 + (size_t)k * 64 + colm];
        }
    } else {
        bool is2 = (r < W1PK + W23PK);
        const float* W = is2 ? fcW2 : fcW3;
        int e = is2 ? (r - W1PK) : (r - W1PK - W23PK);
        int j = e & 7, lane = (e >> 3) & 63, c16 = (e >> 9) & 3, ks = e >> 11;
        int k = ks * 32 + (lane >> 4) * 8 + j;
        int colm = c16 * 16 + (lane & 15);
        val = W[(size_t)layer * 64 * 64 + (size_t)k * 64 + colm];
    }
    Wpk[(size_t)layer * WPK_LAYER + r] = f2bf(val);
}

// ---------------------------------------------------------------------------
// h = xi @ Wl[l] + bl[l]   (N x 32).  float4 stores.
// ---------------------------------------------------------------------------
__global__ __launch_bounds__(256) void h_kernel(
    const float* __restrict__ xi,
    const float* __restrict__ Wl,
    const float* __restrict__ bl,
    float* __restrict__ h)
{
    __shared__ float xs[32 * 64];
    __shared__ float ws[64 * 32];
    int tid = threadIdx.x;
    int nb = blockIdx.x * 32;

    const float4* xsrc = reinterpret_cast<const float4*>(xi + (size_t)nb * 64);
    float4* xd = reinterpret_cast<float4*>(xs);
    #pragma unroll
    for (int i = 0; i < 2; ++i) xd[tid + i * 256] = xsrc[tid + i * 256];
    const float4* wsrc = reinterpret_cast<const float4*>(Wl);
    float4* wd = reinterpret_cast<float4*>(ws);
    #pragma unroll
    for (int i = 0; i < 2; ++i) wd[tid + i * 256] = wsrc[tid + i * 256];
    __syncthreads();

    int c4g = tid & 7;
    int nrow = tid >> 3;
    float4 acc = *reinterpret_cast<const float4*>(bl + c4g * 4);
    const float* xr = xs + nrow * 64;
    #pragma unroll 8
    for (int j = 0; j < 64; ++j) {
        float xv = xr[j];
        float4 wv = *reinterpret_cast<const float4*>(ws + j * 32 + c4g * 4);
        acc.x = fmaf(xv, wv.x, acc.x);
        acc.y = fmaf(xv, wv.y, acc.y);
        acc.z = fmaf(xv, wv.z, acc.z);
        acc.w = fmaf(xv, wv.w, acc.w);
    }
    *reinterpret_cast<float4*>(h + (size_t)(nb + nrow) * 32 + c4g * 4) = acc;
}

// ---------------------------------------------------------------------------
// mi_t[s][e] = bf16(h[dst[e]][16+s]), s-major [16][EPAD].
// Thread-per-edge gather (massive TLP), LDS transpose, coalesced writes.
// Grid = EPAD/256 blocks; e >= E writes zeros.
// Write-out: per block 16 rows x 256 u16 = 512 uint4 -> 2 iters of 256 thr.
// ---------------------------------------------------------------------------
__global__ __launch_bounds__(256) void mi_gather_kernel(
    const int* __restrict__ dst,
    const float* __restrict__ h,
    u16* __restrict__ mi_t)
{
    __shared__ u16 tr[16][264];   // 264 = 33*8: rows 528B (16B-aligned)

    int tid = threadIdx.x;
    int e = blockIdx.x * 256 + tid;

    if (e < N_EDGES) {
        int d = dst[e];
        const float4* hp = reinterpret_cast<const float4*>(h + (size_t)d * 32 + 16);
        float4 v0 = hp[0], v1 = hp[1], v2 = hp[2], v3 = hp[3];
        tr[0][tid]  = f2bf(v0.x); tr[1][tid]  = f2bf(v0.y);
        tr[2][tid]  = f2bf(v0.z); tr[3][tid]  = f2bf(v0.w);
        tr[4][tid]  = f2bf(v1.x); tr[5][tid]  = f2bf(v1.y);
        tr[6][tid]  = f2bf(v1.z); tr[7][tid]  = f2bf(v1.w);
        tr[8][tid]  = f2bf(v2.x); tr[9][tid]  = f2bf(v2.y);
        tr[10][tid] = f2bf(v2.z); tr[11][tid] = f2bf(v2.w);
        tr[12][tid] = f2bf(v3.x); tr[13][tid] = f2bf(v3.y);
        tr[14][tid] = f2bf(v3.z); tr[15][tid] = f2bf(v3.w);
    } else {
        #pragma unroll
        for (int s = 0; s < 16; ++s) tr[s][tid] = 0;
    }
    __syncthreads();

    // 16 rows x 32 uint4/row = 512 uint4; 2 per thread, coalesced per row
    #pragma unroll
    for (int i = 0; i < 2; ++i) {
        int qq = tid + i * 256;
        int s = qq >> 5;          // 32 8-u16 chunks per row
        int c = qq & 31;
        uint4 v = *reinterpret_cast<const uint4*>(&tr[s][c * 8]);
        *reinterpret_cast<uint4*>(mi_t + (size_t)s * EPAD + blockIdx.x * 256 + c * 8) = v;
    }
}

// ---------------------------------------------------------------------------
// FUSED agg + FC chain. Block = 256 thr = 4 waves; 16 nodes per block.
// Phase A (v4, streaming MFMA): per node, agg[nb][s] over K=32 windows:
//   A = WT rows (3 x 16B aligned loads), B = mi_t[s] (1 x 16B aligned load)
//   masked to [e0,e1) via 128-bit shift masks — NO gathers in this kernel.
// Phase B: MFMA FC1(K=672)/FC2/FC3 + xi residual.
// ---------------------------------------------------------------------------
__global__ __launch_bounds__(256) void agg_fc_kernel(
    const u16* __restrict__ WT,             // [48][EPAD] bf16
    const u16* __restrict__ mi_t,           // [16][EPAD] bf16
    const int* __restrict__ row,
    const float* __restrict__ h,            // N x 32 (si staging only)
    const u16* __restrict__ Wpk,            // layer's packed weights
    const float* __restrict__ b1,
    const float* __restrict__ b2,
    const float* __restrict__ b3,
    float* __restrict__ xi)
{
    __shared__ __align__(16) u16 Xs[16][XROW];   // 21760 B
    __shared__ __align__(16) u16 Y1[16 * 72];    //  2304 B
    __shared__ __align__(16) u16 Y2[16 * 72];    //  2304 B
    __shared__ __align__(16) float Yo[16 * 68];  //  4352 B

    int tid = threadIdx.x;
    int wv = tid >> 6;
    int lane = tid & 63;
    int s = lane & 15;      // A row within 16-tile / B col (s feature)
    int kg = lane >> 4;     // k-group 0..3
    int n0 = blockIdx.x * 16;
    int base = n0 + (wv << 2);

    // ---- si staging + zero pad (lane t=kg covers the wave's 4 nodes) ----
    {
        int t = kg;
        u16* xr = &Xs[(wv << 2) + t][0];
        xr[640 + s] = f2bf(h[(size_t)(base + t) * 32 + s]);
        xr[656 + s] = 0;
    }

    // ======== Phase A: streaming MFMA aggregation, 4 nodes per wave ========
    for (int t = 0; t < 4; ++t) {
        int node = base + t;
        int e0 = row[node], e1 = row[node + 1];
        int e0a = e0 & ~7;                       // 16B-aligned window start
        int nks = (e1 - e0a + 31) >> 5;          // K tiles of 32

        f32x4 c0 = {0.f, 0.f, 0.f, 0.f};
        f32x4 c1 = {0.f, 0.f, 0.f, 0.f};
        f32x4 c2 = {0.f, 0.f, 0.f, 0.f};

        for (int kc = 0; kc < nks; ++kc) {
            int eb = e0a + kc * 32 + kg * 8;
            // ---- B fragment: 16B load from mi_t[s], masked to [e0,e1) ----
            uint4 bu = *reinterpret_cast<const uint4*>(mi_t + (size_t)s * EPAD + eb);
            {
                int lo = e0 - eb, hi = e1 - eb;
                ull vA = mge(lo) & ~mge(hi);
                ull vB = mge(lo - 4) & ~mge(hi - 4);
                ull* bp = reinterpret_cast<ull*>(&bu);
                bp[0] &= vA;
                bp[1] &= vB;
            }
            short8v bfrag = *reinterpret_cast<short8v*>(&bu);
            // ---- A fragments: WT rows (16r + s), 16B-aligned loads ----
            const u16* ap = WT + (size_t)s * EPAD + eb;
            short8v a0 = *reinterpret_cast<const short8v*>(ap);
            short8v a1 = *reinterpret_cast<const short8v*>(ap + (size_t)16 * EPAD);
            short8v a2 = *reinterpret_cast<const short8v*>(ap + (size_t)32 * EPAD);
            c0 = __builtin_amdgcn_mfma_f32_16x16x32_bf16(a0, bfrag, c0, 0, 0, 0);
            c1 = __builtin_amdgcn_mfma_f32_16x16x32_bf16(a1, bfrag, c1, 0, 0, 0);
            c2 = __builtin_amdgcn_mfma_f32_16x16x32_bf16(a2, bfrag, c2, 0, 0, 0);
        }

        // ---- write C rows 0..39 into Xs[node] at f' = nb*16 + s ----
        u16* xr = &Xs[(wv << 2) + t][0];
        #pragma unroll
        for (int q = 0; q < 4; ++q) {
            xr[(kg * 4 + q) * 16 + s]      = f2bf(c0[q]);
            xr[(16 + kg * 4 + q) * 16 + s] = f2bf(c1[q]);
        }
        if (kg < 2) {
            #pragma unroll
            for (int q = 0; q < 4; ++q)
                xr[(32 + kg * 4 + q) * 16 + s] = f2bf(c2[q]);
        }
    }
    __syncthreads();

    // ======== Phase B: MFMA FC chain ========
    int w = wv;
    int l = lane;
    int lrow = l & 15;
    int lk = l >> 4;
    int col = w * 16 + lrow;

    const u16* Wpk1 = Wpk;
    const u16* Wpk2 = Wpk + W1PK;
    const u16* Wpk3 = Wpk + W1PK + W23PK;

    // ---- FC1: K = 672 (cols 656..671 zero x zero-packed W) ----
    f32x4 acc;
    {
        float bv = b1[col];
        acc[0] = bv; acc[1] = bv; acc[2] = bv; acc[3] = bv;
    }
    const u16* wp = Wpk1 + ((size_t)w * 64 + l) * 8;
    #pragma unroll
    for (int ks = 0; ks < 21; ++ks) {
        short8v a = *reinterpret_cast<const short8v*>(&Xs[lrow][ks * 32 + lk * 8]);
        short8v b = *reinterpret_cast<const short8v*>(wp + (size_t)ks * 2048);
        acc = __builtin_amdgcn_mfma_f32_16x16x32_bf16(a, b, acc, 0, 0, 0);
    }
    #pragma unroll
    for (int q = 0; q < 4; ++q)
        Y1[(lk * 4 + q) * 72 + col] = f2bf(sspf(acc[q]));
    __syncthreads();

    // ---- FC2: K = 64 ----
    {
        float bv = b2[col];
        acc[0] = bv; acc[1] = bv; acc[2] = bv; acc[3] = bv;
    }
    #pragma unroll
    for (int ks = 0; ks < 2; ++ks) {
        short8v a = *reinterpret_cast<const short8v*>(&Y1[lrow * 72 + ks * 32 + lk * 8]);
        short8v b = *reinterpret_cast<const short8v*>(Wpk2 + ((size_t)(ks * 4 + w) * 64 + l) * 8);
        acc = __builtin_amdgcn_mfma_f32_16x16x32_bf16(a, b, acc, 0, 0, 0);
    }
    #pragma unroll
    for (int q = 0; q < 4; ++q)
        Y2[(lk * 4 + q) * 72 + col] = f2bf(sspf(acc[q]));
    __syncthreads();

    // ---- FC3: K = 64 ----
    {
        float bv = b3[col];
        acc[0] = bv; acc[1] = bv; acc[2] = bv; acc[3] = bv;
    }
    #pragma unroll
    for (int ks = 0; ks < 2; ++ks) {
        short8v a = *reinterpret_cast<const short8v*>(&Y2[lrow * 72 + ks * 32 + lk * 8]);
        short8v b = *reinterpret_cast<const short8v*>(Wpk3 + ((size_t)(ks * 4 + w) * 64 + l) * 8);
        acc = __builtin_amdgcn_mfma_f32_16x16x32_bf16(a, b, acc, 0, 0, 0);
    }
    #pragma unroll
    for (int q = 0; q < 4; ++q)
        Yo[(lk * 4 + q) * 68 + col] = acc[q];
    __syncthreads();

    // ---- residual update, float4 per lane ----
    {
        int rr = tid >> 4;
        int cc = tid & 15;
        float4 dv = *reinterpret_cast<const float4*>(Yo + rr * 68 + cc * 4);
        float4* xpn = reinterpret_cast<float4*>(xi + (size_t)(n0 + rr) * 64 + cc * 4);
        float4 o = *xpn;
        o.x += dv.x; o.y += dv.y; o.z += dv.z; o.w += dv.w;
        *xpn = o;
    }
}

// ---------------------------------------------------------------------------
extern "C" void kernel_launch(void* const* d_in, const int* in_sizes, int n_in,
                              void* d_out, int out_size, void* d_ws, size_t ws_size,
                              hipStream_t stream) {
    const int*   species = (const int*)d_in[0];
    const int*   esrc    = (const int*)d_in[1];
    const int*   edst    = (const int*)d_in[2];
    const float* dist    = (const float*)d_in[3];
    const float* sw      = (const float*)d_in[4];
    const float* bo      = (const float*)d_in[5];
    const float* Wsp     = (const float*)d_in[6];
    const float* Wl      = (const float*)d_in[7];
    const float* bl      = (const float*)d_in[8];
    const float* fcW1    = (const float*)d_in[9];
    const float* fcb1    = (const float*)d_in[10];
    const float* fcW2    = (const float*)d_in[11];
    const float* fcb2    = (const float*)d_in[12];
    const float* fcW3    = (const float*)d_in[13];
    const float* fcb3    = (const float*)d_in[14];
    float* xi = (float*)d_out;

    char* ws = (char*)d_ws;
    u16*   WT   = (u16*)ws;                     // 48*EPAD*2 = 15,384,576 B
    u16*   mi_t = (u16*)(ws + 15384576);        // 16*EPAD*2 =  5,128,192 B
    int*   rowp = (int*)(ws + 20512768);        //     80,128 B
    float* h    = (float*)(ws + 20592896);      //  2,560,000 B
    u16*   Wpk  = (u16*)(ws + 23152896);        //    307,200 B

    hipLaunchKernelGGL(edge_wt_kernel, dim3(EPAD / 512, 40), dim3(256), 0, stream,
                       dist, sw, bo, WT);
    hipLaunchKernelGGL(row_start_kernel, dim3(79), dim3(256), 0, stream,
                       esrc, rowp);
    hipLaunchKernelGGL(xi_init_kernel, dim3(1250), dim3(256), 0, stream,
                       species, Wsp, xi);
    hipLaunchKernelGGL(pack_w_kernel, dim3(600), dim3(256), 0, stream,
                       fcW1, fcW2, fcW3, Wpk);

    for (int l = 0; l < 3; ++l) {
        hipLaunchKernelGGL(h_kernel, dim3(625), dim3(256), 0, stream,
                           xi, Wl + (size_t)l * 64 * 32, bl + (size_t)l * 32, h);
        hipLaunchKernelGGL(mi_gather_kernel, dim3(EPAD / 256), dim3(256), 0, stream,
                           edst, h, mi_t);
        hipLaunchKernelGGL(agg_fc_kernel, dim3(1250), dim3(256), 0, stream,
                           WT, mi_t, rowp, h,
                           Wpk + (size_t)l * WPK_LAYER,
                           fcb1 + (size_t)l * 64, fcb2 + (size_t)l * 64,
                           fcb3 + (size_t)l * 64, xi);
    }
}

// Round 12
// 105.804 us; speedup vs baseline: 1.9633x; 1.3338x over previous
//
#include <hip/hip_runtime.h>
#include <math.h>

#define N_NODES 20000
#define N_EDGES 160000
#define EPAD    160256     // multiple of 256, >=32 slack past E

#define PI_F 3.14159265358979323846f
#define LN2_F 0.69314718055994530942f

#define W1PK 43008         // 21 ksteps * 4 colfrags * 64 lanes * 8 (ushort units)
#define W23PK 4096         // 2 ksteps  * 4 * 64 * 8
#define WPK_LAYER 51200    // per-layer packed weights (ushort units)
#define XROW 680           // LDS X row stride in u16 (1360 B, 16B-aligned)
#define CAP 392            // mi LDS col capacity (stride 392 u16 = 784B: 16B-aligned,
                           // 196 dw % 32 = 4 -> 2-way banks). Fill cap 360.
#define NFILL_MAX 360

typedef short short8v __attribute__((ext_vector_type(8)));
typedef float f32x4 __attribute__((ext_vector_type(4)));
typedef unsigned short u16;
typedef unsigned long long ull;

__device__ __forceinline__ float sspf(float x) {
    return fmaxf(x, 0.0f) + log1pf(expf(-fabsf(x))) - LN2_F;
}
__device__ __forceinline__ u16 f2bf(float f) {
    unsigned int u = __float_as_uint(f);
    return (u16)((u + 0x7fffu + ((u >> 16) & 1u)) >> 16);
}
__device__ __forceinline__ unsigned int pk2(float a, float b) {
    return (unsigned int)f2bf(a) | ((unsigned int)f2bf(b) << 16);
}
// mask of 4 u16 slots: slots j >= t are 0xFFFF (t clamped to [0,4])
__device__ __forceinline__ ull mge(int t) {
    t = t < 0 ? 0 : (t > 4 ? 4 : t);
    return t == 4 ? 0ULL : (~0ULL << (t * 16));
}

// ---------------------------------------------------------------------------
// Single-pass WT build: WT[nb][e] = bf16(sw*sqrt(2/5)*sin((n+1)pi r/5)/r * bo[b])
// [48][EPAD]; rows 40..47 never written; e >= E zeroed. LDS transpose.
// ---------------------------------------------------------------------------
__global__ __launch_bounds__(256) void edge_wt_kernel(
    const float* __restrict__ dist,
    const float* __restrict__ sw,
    const float* __restrict__ bo,
    u16* __restrict__ WT)
{
    __shared__ u16 tr[40][264];
    int tid = threadIdx.x;
    int e = blockIdx.x * 256 + tid;

    if (e < N_EDGES) {
        float r = dist[e];
        float c = sqrtf(0.4f) / r * sw[e];
        float rbv[8];
        #pragma unroll
        for (int n = 0; n < 8; ++n)
            rbv[n] = c * sinf((float)(n + 1) * PI_F * r * 0.2f);
        float bov[5];
        #pragma unroll
        for (int b = 0; b < 5; ++b) bov[b] = bo[(size_t)e * 5 + b];
        #pragma unroll
        for (int n = 0; n < 8; ++n)
            #pragma unroll
            for (int b = 0; b < 5; ++b)
                tr[n * 5 + b][tid] = f2bf(rbv[n] * bov[b]);
    } else {
        #pragma unroll
        for (int j = 0; j < 40; ++j) tr[j][tid] = 0;
    }
    __syncthreads();

    // 40 rows x 32 uint4/row = 1280 uint4; 5 per thread
    #pragma unroll
    for (int i = 0; i < 5; ++i) {
        int qq = tid + i * 256;
        int s = qq >> 5, c = qq & 31;
        uint4 v = *reinterpret_cast<const uint4*>(&tr[s][c * 8]);
        *reinterpret_cast<uint4*>(WT + (size_t)s * EPAD + blockIdx.x * 256 + c * 8) = v;
    }
}

// ---------------------------------------------------------------------------
// CSR offsets from sorted edge_src
// ---------------------------------------------------------------------------
__global__ __launch_bounds__(256) void row_start_kernel(
    const int* __restrict__ src, int* __restrict__ row)
{
    int i = blockIdx.x * blockDim.x + threadIdx.x;
    if (i > N_NODES) return;
    int lo = 0, hi = N_EDGES;
    while (lo < hi) {
        int mid = (lo + hi) >> 1;
        if (src[mid] < i) lo = mid + 1; else hi = mid;
    }
    row[i] = lo;
}

// ---------------------------------------------------------------------------
// Pack FC weights -> bf16 B-fragment layout. X feature f' = nb*16 + s.
// ---------------------------------------------------------------------------
__global__ __launch_bounds__(256) void pack_w_kernel(
    const float* __restrict__ fcW1,
    const float* __restrict__ fcW2,
    const float* __restrict__ fcW3,
    u16* __restrict__ Wpk)
{
    int idx = blockIdx.x * 256 + threadIdx.x;
    if (idx >= 3 * WPK_LAYER) return;
    int layer = idx / WPK_LAYER;
    int r = idx - layer * WPK_LAYER;
    float val = 0.0f;
    if (r < W1PK) {
        int e = r;
        int j = e & 7, lane = (e >> 3) & 63, c16 = (e >> 9) & 3, ks = e >> 11;
        int k = ks * 32 + (lane >> 4) * 8 + j;
        int colm = c16 * 16 + (lane & 15);
        if (k < 640) {
            int nbv = k >> 4, ss = k & 15;
            int nn = nbv / 5, bb = nbv - nn * 5;
            val = fcW1[(size_t)layer * 656 * 64 + (size_t)(nn * 80 + ss * 5 + bb) * 64 + colm];
        } else if (k < 656) {
            val = fcW1[(size_t)layer * 656 * 64 + (size_t)k * 64 + colm];
        }
    } else {
        bool is2 = (r < W1PK + W23PK);
        const float* W = is2 ? fcW2 : fcW3;
        int e = is2 ? (r - W1PK) : (r - W1PK - W23PK);
        int j = e & 7, lane = (e >> 3) & 63, c16 = (e >> 9) & 3, ks = e >> 11;
        int k = ks * 32 + (lane >> 4) * 8 + j;
        int colm = c16 * 16 + (lane & 15);
        val = W[(size_t)layer * 64 * 64 + (size_t)k * 64 + colm];
    }
    Wpk[(size_t)layer * WPK_LAYER + r] = f2bf(val);
}

// ---------------------------------------------------------------------------
// xi = W_species[species]  AND  h0 = xi @ Wl[0] + bl[0].  32 nodes/block.
// ---------------------------------------------------------------------------
__global__ __launch_bounds__(256) void xi_init_h_kernel(
    const int* __restrict__ species,
    const float* __restrict__ Wsp,
    const float* __restrict__ Wl0,   // 64 x 32
    const float* __restrict__ bl0,   // 32
    float* __restrict__ xi,
    float* __restrict__ h)
{
    __shared__ float xs[32 * 64];
    __shared__ float ws[64 * 32];
    int tid = threadIdx.x;
    int nb = blockIdx.x * 32;

    #pragma unroll
    for (int i = 0; i < 2; ++i) {
        int idx = tid + i * 256;           // float4 index in 32x64 tile
        int node = idx >> 4, c4 = idx & 15;
        int sp = species[nb + node];
        float4 v = reinterpret_cast<const float4*>(Wsp + (size_t)sp * 64)[c4];
        reinterpret_cast<float4*>(xs)[idx] = v;
        reinterpret_cast<float4*>(xi)[(size_t)(nb + node) * 16 + c4] = v;
    }
    {
        const float4* wsrc = reinterpret_cast<const float4*>(Wl0);
        float4* wd = reinterpret_cast<float4*>(ws);
        #pragma unroll
        for (int i = 0; i < 2; ++i) wd[tid + i * 256] = wsrc[tid + i * 256];
    }
    __syncthreads();

    int c4g = tid & 7;
    int nrow = tid >> 3;
    float4 acc = *reinterpret_cast<const float4*>(bl0 + c4g * 4);
    const float* xr = xs + nrow * 64;
    #pragma unroll 8
    for (int j = 0; j < 64; ++j) {
        float xv = xr[j];
        float4 wv = *reinterpret_cast<const float4*>(ws + j * 32 + c4g * 4);
        acc.x = fmaf(xv, wv.x, acc.x);
        acc.y = fmaf(xv, wv.y, acc.y);
        acc.z = fmaf(xv, wv.z, acc.z);
        acc.w = fmaf(xv, wv.w, acc.w);
    }
    *reinterpret_cast<float4*>(h + (size_t)(nb + nrow) * 32 + c4g * 4) = acc;
}

// ---------------------------------------------------------------------------
// FULLY FUSED per-layer kernel. Block = 256 thr = 4 waves; 16 nodes.
// 1) block-local mi gather: edges [row[n0], row[n0+16]) -> LDS [16][CAP]
// 2) phase A streaming MFMA aggregation (A=WT global, B=mi LDS, masked)
// 3) FC1/FC2/FC3 MFMA chain + xi residual
// 4) (do_h) h_next = xi_new @ Wl_next + bl_next for own 16 nodes
// LDS aliasing: Y1/Y2/Yo live in dead mi region; Wl/Xn in dead Xs region.
// ---------------------------------------------------------------------------
__global__ __launch_bounds__(256) void agg_fc_fused(
    const u16* __restrict__ WT,             // [48][EPAD] bf16
    const int* __restrict__ row,
    const int* __restrict__ dst,
    const float* __restrict__ h_in,         // N x 32
    float* __restrict__ h_out,              // N x 32 (next layer)
    const u16* __restrict__ Wpk,
    const float* __restrict__ b1,
    const float* __restrict__ b2,
    const float* __restrict__ b3,
    const float* __restrict__ Wl_next,      // 64 x 32 (if do_h)
    const float* __restrict__ bl_next,      // 32
    int do_h,
    float* __restrict__ xi)
{
    __shared__ __align__(16) char smem[21760 + 16 * CAP * 2];   // 34304 B
    u16 (*Xs)[XROW] = reinterpret_cast<u16(*)[XROW]>(smem);
    u16* mi  = reinterpret_cast<u16*>(smem + 21760);            // [16][CAP]
    u16* Y1  = reinterpret_cast<u16*>(smem + 21760);            // aliases mi
    u16* Y2  = reinterpret_cast<u16*>(smem + 21760 + 2304);
    float* Yo = reinterpret_cast<float*>(smem + 21760 + 4608);  // 16 x 68 f32
    float* Wlds = reinterpret_cast<float*>(smem);               // aliases Xs
    float* Xn   = reinterpret_cast<float*>(smem + 8192);        // 16 x 68 f32

    int tid = threadIdx.x;
    int wv = tid >> 6;
    int lane = tid & 63;
    int s = lane & 15;
    int kg = lane >> 4;
    int n0 = blockIdx.x * 16;
    int base = n0 + (wv << 2);

    int E0 = row[n0];
    int E1 = row[n0 + 16];
    int G0 = E0 & ~7;
    int nfill = E1 - G0;
    if (nfill > NFILL_MAX) nfill = NFILL_MAX;

    // ---- si staging + zero pad ----
    {
        int t = kg;
        u16* xr = &Xs[(wv << 2) + t][0];
        xr[640 + s] = f2bf(h_in[(size_t)(base + t) * 32 + s]);
        xr[656 + s] = 0;
    }

    // ---- block-local mi gather: thread-per-edge ----
    for (int i = tid; i < nfill; i += 256) {
        int d = dst[G0 + i];
        const float4* hp = reinterpret_cast<const float4*>(h_in + (size_t)d * 32 + 16);
        float4 v0 = hp[0], v1 = hp[1], v2 = hp[2], v3 = hp[3];
        u16* col = mi + i;
        col[0 * CAP]  = f2bf(v0.x); col[1 * CAP]  = f2bf(v0.y);
        col[2 * CAP]  = f2bf(v0.z); col[3 * CAP]  = f2bf(v0.w);
        col[4 * CAP]  = f2bf(v1.x); col[5 * CAP]  = f2bf(v1.y);
        col[6 * CAP]  = f2bf(v1.z); col[7 * CAP]  = f2bf(v1.w);
        col[8 * CAP]  = f2bf(v2.x); col[9 * CAP]  = f2bf(v2.y);
        col[10 * CAP] = f2bf(v2.z); col[11 * CAP] = f2bf(v2.w);
        col[12 * CAP] = f2bf(v3.x); col[13 * CAP] = f2bf(v3.y);
        col[14 * CAP] = f2bf(v3.z); col[15 * CAP] = f2bf(v3.w);
    }
    __syncthreads();

    // ======== Phase A: streaming MFMA aggregation ========
    for (int t = 0; t < 4; ++t) {
        int node = base + t;
        int e0 = row[node], e1 = row[node + 1];
        int e0a = e0 & ~7;
        int L0 = e0a - G0;                       // local aligned start (8-aligned)
        int nks = (e1 - e0a + 31) >> 5;

        f32x4 c0 = {0.f, 0.f, 0.f, 0.f};
        f32x4 c1 = {0.f, 0.f, 0.f, 0.f};
        f32x4 c2 = {0.f, 0.f, 0.f, 0.f};

        for (int kc = 0; kc < nks; ++kc) {
            int ebg = e0a + kc * 32 + kg * 8;    // global (WT, masks)
            int ebl = L0 + kc * 32 + kg * 8;     // local (mi LDS)
            uint4 bu = *reinterpret_cast<const uint4*>(mi + s * CAP + ebl);
            {
                int lo = e0 - ebg, hi = e1 - ebg;
                ull vA = mge(lo) & ~mge(hi);
                ull vB = mge(lo - 4) & ~mge(hi - 4);
                ull* bp = reinterpret_cast<ull*>(&bu);
                bp[0] &= vA;
                bp[1] &= vB;
            }
            short8v bfrag = *reinterpret_cast<short8v*>(&bu);
            const u16* ap = WT + (size_t)s * EPAD + ebg;
            short8v a0 = *reinterpret_cast<const short8v*>(ap);
            short8v a1 = *reinterpret_cast<const short8v*>(ap + (size_t)16 * EPAD);
            short8v a2 = *reinterpret_cast<const short8v*>(ap + (size_t)32 * EPAD);
            c0 = __builtin_amdgcn_mfma_f32_16x16x32_bf16(a0, bfrag, c0, 0, 0, 0);
            c1 = __builtin_amdgcn_mfma_f32_16x16x32_bf16(a1, bfrag, c1, 0, 0, 0);
            c2 = __builtin_amdgcn_mfma_f32_16x16x32_bf16(a2, bfrag, c2, 0, 0, 0);
        }

        u16* xr = &Xs[(wv << 2) + t][0];
        #pragma unroll
        for (int q = 0; q < 4; ++q) {
            xr[(kg * 4 + q) * 16 + s]      = f2bf(c0[q]);
            xr[(16 + kg * 4 + q) * 16 + s] = f2bf(c1[q]);
        }
        if (kg < 2) {
            #pragma unroll
            for (int q = 0; q < 4; ++q)
                xr[(32 + kg * 4 + q) * 16 + s] = f2bf(c2[q]);
        }
    }
    __syncthreads();

    // ======== FC chain ========
    int w = wv;
    int l = lane;
    int lrow = l & 15;
    int lk = l >> 4;
    int col = w * 16 + lrow;

    const u16* Wpk1 = Wpk;
    const u16* Wpk2 = Wpk + W1PK;
    const u16* Wpk3 = Wpk + W1PK + W23PK;

    // ---- FC1: K = 672 ----
    f32x4 acc;
    {
        float bv = b1[col];
        acc[0] = bv; acc[1] = bv; acc[2] = bv; acc[3] = bv;
    }
    const u16* wp = Wpk1 + ((size_t)w * 64 + l) * 8;
    #pragma unroll
    for (int ks = 0; ks < 21; ++ks) {
        short8v a = *reinterpret_cast<const short8v*>(&Xs[lrow][ks * 32 + lk * 8]);
        short8v b = *reinterpret_cast<const short8v*>(wp + (size_t)ks * 2048);
        acc = __builtin_amdgcn_mfma_f32_16x16x32_bf16(a, b, acc, 0, 0, 0);
    }
    __syncthreads();   // mi region fully dead before Y1 writes (mi aliased)
    #pragma unroll
    for (int q = 0; q < 4; ++q)
        Y1[(lk * 4 + q) * 72 + col] = f2bf(sspf(acc[q]));
    __syncthreads();

    // stage Wl_next into dead Xs region (concurrent with FC2/FC3)
    if (do_h) {
        float4* wd = reinterpret_cast<float4*>(Wlds);
        const float4* wsrc = reinterpret_cast<const float4*>(Wl_next);
        wd[tid] = wsrc[tid];
        wd[tid + 256] = wsrc[tid + 256];
    }

    // ---- FC2: K = 64 ----
    {
        float bv = b2[col];
        acc[0] = bv; acc[1] = bv; acc[2] = bv; acc[3] = bv;
    }
    #pragma unroll
    for (int ks = 0; ks < 2; ++ks) {
        short8v a = *reinterpret_cast<const short8v*>(&Y1[lrow * 72 + ks * 32 + lk * 8]);
        short8v b = *reinterpret_cast<const short8v*>(Wpk2 + ((size_t)(ks * 4 + w) * 64 + l) * 8);
        acc = __builtin_amdgcn_mfma_f32_16x16x32_bf16(a, b, acc, 0, 0, 0);
    }
    __syncthreads();
    #pragma unroll
    for (int q = 0; q < 4; ++q)
        Y2[(lk * 4 + q) * 72 + col] = f2bf(sspf(acc[q]));
    __syncthreads();

    // ---- FC3: K = 64 ----
    {
        float bv = b3[col];
        acc[0] = bv; acc[1] = bv; acc[2] = bv; acc[3] = bv;
    }
    #pragma unroll
    for (int ks = 0; ks < 2; ++ks) {
        short8v a = *reinterpret_cast<const short8v*>(&Y2[lrow * 72 + ks * 32 + lk * 8]);
        short8v b = *reinterpret_cast<const short8v*>(Wpk3 + ((size_t)(ks * 4 + w) * 64 + l) * 8);
        acc = __builtin_amdgcn_mfma_f32_16x16x32_bf16(a, b, acc, 0, 0, 0);
    }
    #pragma unroll
    for (int q = 0; q < 4; ++q)
        Yo[(lk * 4 + q) * 68 + col] = acc[q];
    __syncthreads();

    // ---- residual update (+ stash xi_new for h epilogue) ----
    {
        int rr = tid >> 4;
        int cc = tid & 15;
        float4 dv = *reinterpret_cast<const float4*>(Yo + rr * 68 + cc * 4);
        float4* xpn = reinterpret_cast<float4*>(xi + (size_t)(n0 + rr) * 64 + cc * 4);
        float4 o = *xpn;
        o.x += dv.x; o.y += dv.y; o.z += dv.z; o.w += dv.w;
        *xpn = o;
        if (do_h)
            *reinterpret_cast<float4*>(Xn + rr * 68 + cc * 4) = o;
    }

    // ---- h_next for own 16 nodes ----
    if (do_h) {
        __syncthreads();
        int node = tid >> 4;
        int c2 = (tid & 15) * 2;
        const float* xnr = Xn + node * 68;
        float h0 = bl_next[c2], h1 = bl_next[c2 + 1];
        #pragma unroll 8
        for (int j = 0; j < 64; ++j) {
            float xv = xnr[j];
            h0 = fmaf(xv, Wlds[j * 32 + c2], h0);
            h1 = fmaf(xv, Wlds[j * 32 + c2 + 1], h1);
        }
        *reinterpret_cast<float2*>(h_out + (size_t)(n0 + node) * 32 + c2) =
            make_float2(h0, h1);
    }
}

// ---------------------------------------------------------------------------
extern "C" void kernel_launch(void* const* d_in, const int* in_sizes, int n_in,
                              void* d_out, int out_size, void* d_ws, size_t ws_size,
                              hipStream_t stream) {
    const int*   species = (const int*)d_in[0];
    const int*   esrc    = (const int*)d_in[1];
    const int*   edst    = (const int*)d_in[2];
    const float* dist    = (const float*)d_in[3];
    const float* sw      = (const float*)d_in[4];
    const float* bo      = (const float*)d_in[5];
    const float* Wsp     = (const float*)d_in[6];
    const float* Wl      = (const float*)d_in[7];
    const float* bl      = (const float*)d_in[8];
    const float* fcW1    = (const float*)d_in[9];
    const float* fcb1    = (const float*)d_in[10];
    const float* fcW2    = (const float*)d_in[11];
    const float* fcb2    = (const float*)d_in[12];
    const float* fcW3    = (const float*)d_in[13];
    const float* fcb3    = (const float*)d_in[14];
    float* xi = (float*)d_out;

    char* ws = (char*)d_ws;
    u16*   WT   = (u16*)ws;                     // 48*EPAD*2 = 15,384,576 B
    int*   rowp = (int*)(ws + 15384576);        //     80,128 B
    float* h0   = (float*)(ws + 15464704);      //  2,560,000 B
    float* h1   = (float*)(ws + 18024704);      //  2,560,000 B
    u16*   Wpk  = (u16*)(ws + 20584704);        //    307,200 B

    hipLaunchKernelGGL(edge_wt_kernel, dim3(EPAD / 256), dim3(256), 0, stream,
                       dist, sw, bo, WT);
    hipLaunchKernelGGL(row_start_kernel, dim3(79), dim3(256), 0, stream,
                       esrc, rowp);
    hipLaunchKernelGGL(pack_w_kernel, dim3(600), dim3(256), 0, stream,
                       fcW1, fcW2, fcW3, Wpk);
    hipLaunchKernelGGL(xi_init_h_kernel, dim3(625), dim3(256), 0, stream,
                       species, Wsp, Wl, bl, xi, h0);

    float* hbuf[2] = {h0, h1};
    for (int l = 0; l < 3; ++l) {
        int do_h = (l < 2) ? 1 : 0;
        hipLaunchKernelGGL(agg_fc_fused, dim3(1250), dim3(256), 0, stream,
                           WT, rowp, edst,
                           hbuf[l & 1], hbuf[(l + 1) & 1],
                           Wpk + (size_t)l * WPK_LAYER,
                           fcb1 + (size_t)l * 64, fcb2 + (size_t)l * 64,
                           fcb3 + (size_t)l * 64,
                           Wl + (size_t)(l + 1) * 64 * 32,
                           bl + (size_t)(l + 1) * 32,
                           do_h, xi);
    }
}

// Round 15
// 95.542 us; speedup vs baseline: 2.1742x; 1.1074x over previous
//
#include <hip/hip_runtime.h>
#include <math.h>

#define N_NODES 20000
#define N_EDGES 160000
#define EPAD    160256
#define NTILES  1250

#define PI_F 3.14159265358979323846f
#define LN2_F 0.69314718055994530942f

#define W1PK 43008
#define W23PK 4096
#define WPK_LAYER 51200
#define XROW 680           // LDS X row stride in u16
#define CAP 392            // mi LDS row stride in u16 (R12-proven)
#define NFILL_MAX 360

#define NW_EDGE 626        // edge_wt tiles
#define NW_XI   625        // xi_init_h tiles
#define NW_PACK 600        // pack_w tiles
#define NW_ROW  79         // row_start tiles
#define NW_TOTAL (NW_EDGE + NW_XI + NW_PACK + NW_ROW)   // 1930

typedef short short8v __attribute__((ext_vector_type(8)));
typedef float f32x4 __attribute__((ext_vector_type(4)));
typedef unsigned short u16;
typedef unsigned long long ull;

__device__ __forceinline__ float sspf(float x) {
    return fmaxf(x, 0.0f) + log1pf(expf(-fabsf(x))) - LN2_F;
}
__device__ __forceinline__ u16 f2bf(float f) {
    unsigned int u = __float_as_uint(f);
    return (u16)((u + 0x7fffu + ((u >> 16) & 1u)) >> 16);
}
__device__ __forceinline__ unsigned int pk2(float a, float b) {
    return (unsigned int)f2bf(a) | ((unsigned int)f2bf(b) << 16);
}
// mask of 4 u16 slots: slots j >= t are 0xFFFF (t clamped to [0,4])
__device__ __forceinline__ ull mge(int t) {
    t = t < 0 ? 0 : (t > 4 ? 4 : t);
    return t == 4 ? 0ULL : (~0ULL << (t * 16));
}

// ======================= setup works (shared smem) ==========================

__device__ void edge_wt_work(int blk, const float* __restrict__ dist,
                             const float* __restrict__ sw,
                             const float* __restrict__ bo,
                             u16* __restrict__ WT, char* smem)
{
    u16 (*tr)[264] = reinterpret_cast<u16(*)[264]>(smem);   // 21120 B
    int tid = threadIdx.x;
    int e = blk * 256 + tid;

    if (e < N_EDGES) {
        float r = dist[e];
        float c = sqrtf(0.4f) / r * sw[e];
        float rbv[8];
        #pragma unroll
        for (int n = 0; n < 8; ++n)
            rbv[n] = c * sinf((float)(n + 1) * PI_F * r * 0.2f);
        float bov[5];
        #pragma unroll
        for (int b = 0; b < 5; ++b) bov[b] = bo[(size_t)e * 5 + b];
        #pragma unroll
        for (int n = 0; n < 8; ++n)
            #pragma unroll
            for (int b = 0; b < 5; ++b)
                tr[n * 5 + b][tid] = f2bf(rbv[n] * bov[b]);
    } else {
        #pragma unroll
        for (int j = 0; j < 40; ++j) tr[j][tid] = 0;
    }
    __syncthreads();

    #pragma unroll
    for (int i = 0; i < 5; ++i) {
        int qq = tid + i * 256;
        int s = qq >> 5, c = qq & 31;
        uint4 v = *reinterpret_cast<const uint4*>(&tr[s][c * 8]);
        *reinterpret_cast<uint4*>(WT + (size_t)s * EPAD + blk * 256 + c * 8) = v;
    }
}

__device__ void row_start_work(int blk, const int* __restrict__ src,
                               int* __restrict__ row)
{
    int i = blk * 256 + threadIdx.x;
    if (i > N_NODES) return;
    int lo = 0, hi = N_EDGES;
    while (lo < hi) {
        int mid = (lo + hi) >> 1;
        if (src[mid] < i) lo = mid + 1; else hi = mid;
    }
    row[i] = lo;
}

__device__ void pack_w_work(int blk, const float* __restrict__ fcW1,
                            const float* __restrict__ fcW2,
                            const float* __restrict__ fcW3,
                            u16* __restrict__ Wpk)
{
    int idx = blk * 256 + threadIdx.x;
    if (idx >= 3 * WPK_LAYER) return;
    int layer = idx / WPK_LAYER;
    int r = idx - layer * WPK_LAYER;
    float val = 0.0f;
    if (r < W1PK) {
        int e = r;
        int j = e & 7, lane = (e >> 3) & 63, c16 = (e >> 9) & 3, ks = e >> 11;
        int k = ks * 32 + (lane >> 4) * 8 + j;
        int colm = c16 * 16 + (lane & 15);
        if (k < 640) {
            int nbv = k >> 4, ss = k & 15;
            int nn = nbv / 5, bb = nbv - nn * 5;
            val = fcW1[(size_t)layer * 656 * 64 + (size_t)(nn * 80 + ss * 5 + bb) * 64 + colm];
        } else if (k < 656) {
            val = fcW1[(size_t)layer * 656 * 64 + (size_t)k * 64 + colm];
        }
    } else {
        bool is2 = (r < W1PK + W23PK);
        const float* W = is2 ? fcW2 : fcW3;
        int e = is2 ? (r - W1PK) : (r - W1PK - W23PK);
        int j = e & 7, lane = (e >> 3) & 63, c16 = (e >> 9) & 3, ks = e >> 11;
        int k = ks * 32 + (lane >> 4) * 8 + j;
        int colm = c16 * 16 + (lane & 15);
        val = W[(size_t)layer * 64 * 64 + (size_t)k * 64 + colm];
    }
    Wpk[(size_t)layer * WPK_LAYER + r] = f2bf(val);
}

__device__ void xi_init_h_work(int blk, const int* __restrict__ species,
                               const float* __restrict__ Wsp,
                               const float* __restrict__ Wl0,
                               const float* __restrict__ bl0,
                               float* __restrict__ xi,
                               float* __restrict__ h, char* smem)
{
    float* xs = reinterpret_cast<float*>(smem);            //  8192 B
    float* ws = reinterpret_cast<float*>(smem + 8192);     //  8192 B
    int tid = threadIdx.x;
    int nb = blk * 32;

    #pragma unroll
    for (int i = 0; i < 2; ++i) {
        int idx = tid + i * 256;
        int node = idx >> 4, c4 = idx & 15;
        int sp = species[nb + node];
        float4 v = reinterpret_cast<const float4*>(Wsp + (size_t)sp * 64)[c4];
        reinterpret_cast<float4*>(xs)[idx] = v;
        reinterpret_cast<float4*>(xi)[(size_t)(nb + node) * 16 + c4] = v;
    }
    {
        const float4* wsrc = reinterpret_cast<const float4*>(Wl0);
        float4* wd = reinterpret_cast<float4*>(ws);
        #pragma unroll
        for (int i = 0; i < 2; ++i) wd[tid + i * 256] = wsrc[tid + i * 256];
    }
    __syncthreads();

    int c4g = tid & 7;
    int nrow = tid >> 3;
    float4 acc = *reinterpret_cast<const float4*>(bl0 + c4g * 4);
    const float* xr = xs + nrow * 64;
    #pragma unroll 8
    for (int j = 0; j < 64; ++j) {
        float xv = xr[j];
        float4 wv = *reinterpret_cast<const float4*>(ws + j * 32 + c4g * 4);
        acc.x = fmaf(xv, wv.x, acc.x);
        acc.y = fmaf(xv, wv.y, acc.y);
        acc.z = fmaf(xv, wv.z, acc.z);
        acc.w = fmaf(xv, wv.w, acc.w);
    }
    *reinterpret_cast<float4*>(h + (size_t)(nb + nrow) * 32 + c4g * 4) = acc;
}

// ======================= merged setup kernel (1 dispatch) ===================
__global__ __launch_bounds__(256) void setup_kernel(
    const float* __restrict__ dist, const float* __restrict__ sw,
    const float* __restrict__ bo, u16* __restrict__ WT,
    const int* __restrict__ species, const float* __restrict__ Wsp,
    const float* __restrict__ Wl0, const float* __restrict__ bl0,
    float* __restrict__ xi, float* __restrict__ h0,
    const float* __restrict__ fcW1, const float* __restrict__ fcW2,
    const float* __restrict__ fcW3, u16* __restrict__ Wpk,
    const int* __restrict__ esrc, int* __restrict__ rowp)
{
    __shared__ __align__(16) char smem[21760];
    int wk = blockIdx.x;
    if (wk < NW_EDGE)
        edge_wt_work(wk, dist, sw, bo, WT, smem);
    else if (wk < NW_EDGE + NW_XI)
        xi_init_h_work(wk - NW_EDGE, species, Wsp, Wl0, bl0, xi, h0, smem);
    else if (wk < NW_EDGE + NW_XI + NW_PACK)
        pack_w_work(wk - NW_EDGE - NW_XI, fcW1, fcW2, fcW3, Wpk);
    else
        row_start_work(wk - NW_EDGE - NW_XI - NW_PACK, esrc, rowp);
}

// ======================= fused per-layer kernel (R12-proven) ================
__global__ __launch_bounds__(256) void agg_fc_fused(
    const u16* __restrict__ WT,             // [48][EPAD] bf16 (rows 40..47 unused)
    const int* __restrict__ row,
    const int* __restrict__ dst,
    const float* __restrict__ h_in,         // N x 32
    float* __restrict__ h_out,              // N x 32 (next layer)
    const u16* __restrict__ Wpk,
    const float* __restrict__ b1,
    const float* __restrict__ b2,
    const float* __restrict__ b3,
    const float* __restrict__ Wl_next,      // 64 x 32 (if do_h)
    const float* __restrict__ bl_next,      // 32
    int do_h,
    float* __restrict__ xi)
{
    __shared__ __align__(16) char smem[21760 + 16 * CAP * 2];   // 34304 B
    u16 (*Xs)[XROW] = reinterpret_cast<u16(*)[XROW]>(smem);
    u16* mi  = reinterpret_cast<u16*>(smem + 21760);            // [16][CAP]
    u16* Y1  = reinterpret_cast<u16*>(smem + 21760);            // aliases mi
    u16* Y2  = reinterpret_cast<u16*>(smem + 21760 + 2304);
    float* Yo = reinterpret_cast<float*>(smem + 21760 + 4608);  // 16 x 68 f32
    float* Wlds = reinterpret_cast<float*>(smem);               // aliases Xs
    float* Xn   = reinterpret_cast<float*>(smem + 8192);        // 16 x 68 f32

    int tid = threadIdx.x;
    int wv = tid >> 6;
    int lane = tid & 63;
    int s = lane & 15;
    int kg = lane >> 4;
    int n0 = blockIdx.x * 16;
    int base = n0 + (wv << 2);

    int E0 = row[n0];
    int E1 = row[n0 + 16];
    int G0 = E0 & ~7;
    int nfill = E1 - G0;
    if (nfill > NFILL_MAX) nfill = NFILL_MAX;

    // ---- si staging + zero pad ----
    {
        int t = kg;
        u16* xr = &Xs[(wv << 2) + t][0];
        xr[640 + s] = f2bf(h_in[(size_t)(base + t) * 32 + s]);
        xr[656 + s] = 0;
    }

    // ---- block-local mi gather: thread-per-edge ----
    for (int i = tid; i < nfill; i += 256) {
        int d = dst[G0 + i];
        const float4* hp = reinterpret_cast<const float4*>(h_in + (size_t)d * 32 + 16);
        float4 v0 = hp[0], v1 = hp[1], v2 = hp[2], v3 = hp[3];
        u16* col = mi + i;
        col[0 * CAP]  = f2bf(v0.x); col[1 * CAP]  = f2bf(v0.y);
        col[2 * CAP]  = f2bf(v0.z); col[3 * CAP]  = f2bf(v0.w);
        col[4 * CAP]  = f2bf(v1.x); col[5 * CAP]  = f2bf(v1.y);
        col[6 * CAP]  = f2bf(v1.z); col[7 * CAP]  = f2bf(v1.w);
        col[8 * CAP]  = f2bf(v2.x); col[9 * CAP]  = f2bf(v2.y);
        col[10 * CAP] = f2bf(v2.z); col[11 * CAP] = f2bf(v2.w);
        col[12 * CAP] = f2bf(v3.x); col[13 * CAP] = f2bf(v3.y);
        col[14 * CAP] = f2bf(v3.z); col[15 * CAP] = f2bf(v3.w);
    }
    __syncthreads();

    // ======== Phase A: streaming MFMA aggregation ========
    for (int t = 0; t < 4; ++t) {
        int node = base + t;
        int e0 = row[node], e1 = row[node + 1];
        int e0a = e0 & ~7;
        int L0 = e0a - G0;                       // local aligned start (8-aligned)
        int nks = (e1 - e0a + 31) >> 5;

        f32x4 c0 = {0.f, 0.f, 0.f, 0.f};
        f32x4 c1 = {0.f, 0.f, 0.f, 0.f};
        f32x4 c2 = {0.f, 0.f, 0.f, 0.f};

        for (int kc = 0; kc < nks; ++kc) {
            int ebg = e0a + kc * 32 + kg * 8;    // global (WT, masks)
            int ebl = L0 + kc * 32 + kg * 8;     // local (mi LDS)
            uint4 bu = *reinterpret_cast<const uint4*>(mi + s * CAP + ebl);
            {
                int lo = e0 - ebg, hi = e1 - ebg;
                ull vA = mge(lo) & ~mge(hi);
                ull vB = mge(lo - 4) & ~mge(hi - 4);
                ull* bp = reinterpret_cast<ull*>(&bu);
                bp[0] &= vA;
                bp[1] &= vB;
            }
            short8v bfrag = *reinterpret_cast<short8v*>(&bu);
            const u16* ap = WT + (size_t)s * EPAD + ebg;
            short8v a0 = *reinterpret_cast<const short8v*>(ap);
            short8v a1 = *reinterpret_cast<const short8v*>(ap + (size_t)16 * EPAD);
            short8v a2 = *reinterpret_cast<const short8v*>(ap + (size_t)32 * EPAD);
            c0 = __builtin_amdgcn_mfma_f32_16x16x32_bf16(a0, bfrag, c0, 0, 0, 0);
            c1 = __builtin_amdgcn_mfma_f32_16x16x32_bf16(a1, bfrag, c1, 0, 0, 0);
            c2 = __builtin_amdgcn_mfma_f32_16x16x32_bf16(a2, bfrag, c2, 0, 0, 0);
        }

        u16* xr = &Xs[(wv << 2) + t][0];
        #pragma unroll
        for (int q = 0; q < 4; ++q) {
            xr[(kg * 4 + q) * 16 + s]      = f2bf(c0[q]);
            xr[(16 + kg * 4 + q) * 16 + s] = f2bf(c1[q]);
        }
        if (kg < 2) {
            #pragma unroll
            for (int q = 0; q < 4; ++q)
                xr[(32 + kg * 4 + q) * 16 + s] = f2bf(c2[q]);
        }
    }
    __syncthreads();

    // ======== FC chain ========
    int w = wv;
    int lrow = lane & 15;
    int lk = lane >> 4;
    int col = w * 16 + lrow;

    const u16* Wpk1 = Wpk;
    const u16* Wpk2 = Wpk + W1PK;
    const u16* Wpk3 = Wpk + W1PK + W23PK;

    // ---- FC1: K = 672 ----
    f32x4 acc;
    {
        float bv = b1[col];
        acc[0] = bv; acc[1] = bv; acc[2] = bv; acc[3] = bv;
    }
    const u16* wp = Wpk1 + ((size_t)w * 64 + lane) * 8;
    #pragma unroll
    for (int ks = 0; ks < 21; ++ks) {
        short8v a = *reinterpret_cast<const short8v*>(&Xs[lrow][ks * 32 + lk * 8]);
        short8v b = *reinterpret_cast<const short8v*>(wp + (size_t)ks * 2048);
        acc = __builtin_amdgcn_mfma_f32_16x16x32_bf16(a, b, acc, 0, 0, 0);
    }
    __syncthreads();   // mi region fully dead before Y1 writes (mi aliased)
    #pragma unroll
    for (int q = 0; q < 4; ++q)
        Y1[(lk * 4 + q) * 72 + col] = f2bf(sspf(acc[q]));
    __syncthreads();

    // stage Wl_next into dead Xs region (concurrent with FC2/FC3)
    if (do_h) {
        const float4* wsrc = reinterpret_cast<const float4*>(Wl_next);
        float4* wd = reinterpret_cast<float4*>(Wlds);
        wd[tid] = wsrc[tid];
        wd[tid + 256] = wsrc[tid + 256];
    }

    // ---- FC2: K = 64 ----
    {
        float bv = b2[col];
        acc[0] = bv; acc[1] = bv; acc[2] = bv; acc[3] = bv;
    }
    #pragma unroll
    for (int ks = 0; ks < 2; ++ks) {
        short8v a = *reinterpret_cast<const short8v*>(&Y1[lrow * 72 + ks * 32 + lk * 8]);
        short8v b = *reinterpret_cast<const short8v*>(Wpk2 + ((size_t)(ks * 4 + w) * 64 + lane) * 8);
        acc = __builtin_amdgcn_mfma_f32_16x16x32_bf16(a, b, acc, 0, 0, 0);
    }
    __syncthreads();
    #pragma unroll
    for (int q = 0; q < 4; ++q)
        Y2[(lk * 4 + q) * 72 + col] = f2bf(sspf(acc[q]));
    __syncthreads();

    // ---- FC3: K = 64 ----
    {
        float bv = b3[col];
        acc[0] = bv; acc[1] = bv; acc[2] = bv; acc[3] = bv;
    }
    #pragma unroll
    for (int ks = 0; ks < 2; ++ks) {
        short8v a = *reinterpret_cast<const short8v*>(&Y2[lrow * 72 + ks * 32 + lk * 8]);
        short8v b = *reinterpret_cast<const short8v*>(Wpk3 + ((size_t)(ks * 4 + w) * 64 + lane) * 8);
        acc = __builtin_amdgcn_mfma_f32_16x16x32_bf16(a, b, acc, 0, 0, 0);
    }
    #pragma unroll
    for (int q = 0; q < 4; ++q)
        Yo[(lk * 4 + q) * 68 + col] = acc[q];
    __syncthreads();

    // ---- residual update (+ stash xi_new for h epilogue) ----
    {
        int rr = tid >> 4;
        int cc = tid & 15;
        float4 dv = *reinterpret_cast<const float4*>(Yo + rr * 68 + cc * 4);
        float4* xpn = reinterpret_cast<float4*>(xi + (size_t)(n0 + rr) * 64 + cc * 4);
        float4 o = *xpn;
        o.x += dv.x; o.y += dv.y; o.z += dv.z; o.w += dv.w;
        *xpn = o;
        if (do_h)
            *reinterpret_cast<float4*>(Xn + rr * 68 + cc * 4) = o;
    }

    // ---- h_next for own 16 nodes ----
    if (do_h) {
        __syncthreads();
        int node = tid >> 4;
        int c2 = (tid & 15) * 2;
        const float* xnr = Xn + node * 68;
        float h0 = bl_next[c2], h1 = bl_next[c2 + 1];
        #pragma unroll 8
        for (int j = 0; j < 64; ++j) {
            float xv = xnr[j];
            h0 = fmaf(xv, Wlds[j * 32 + c2], h0);
            h1 = fmaf(xv, Wlds[j * 32 + c2 + 1], h1);
        }
        *reinterpret_cast<float2*>(h_out + (size_t)(n0 + node) * 32 + c2) =
            make_float2(h0, h1);
    }
}

// ---------------------------------------------------------------------------
extern "C" void kernel_launch(void* const* d_in, const int* in_sizes, int n_in,
                              void* d_out, int out_size, void* d_ws, size_t ws_size,
                              hipStream_t stream) {
    const int*   species = (const int*)d_in[0];
    const int*   esrc    = (const int*)d_in[1];
    const int*   edst    = (const int*)d_in[2];
    const float* dist    = (const float*)d_in[3];
    const float* sw      = (const float*)d_in[4];
    const float* bo      = (const float*)d_in[5];
    const float* Wsp     = (const float*)d_in[6];
    const float* Wl      = (const float*)d_in[7];
    const float* bl      = (const float*)d_in[8];
    const float* fcW1    = (const float*)d_in[9];
    const float* fcb1    = (const float*)d_in[10];
    const float* fcW2    = (const float*)d_in[11];
    const float* fcb2    = (const float*)d_in[12];
    const float* fcW3    = (const float*)d_in[13];
    const float* fcb3    = (const float*)d_in[14];
    float* xi = (float*)d_out;

    char* ws = (char*)d_ws;
    u16*   WT   = (u16*)ws;                     // 48*EPAD*2 = 15,384,576 B
    int*   rowp = (int*)(ws + 15384576);        //     80,128 B
    float* h0   = (float*)(ws + 15464704);      //  2,560,000 B
    float* h1   = (float*)(ws + 18024704);      //  2,560,000 B
    u16*   Wpk  = (u16*)(ws + 20584704);        //    307,200 B

    hipLaunchKernelGGL(setup_kernel, dim3(NW_TOTAL), dim3(256), 0, stream,
                       dist, sw, bo, WT,
                       species, Wsp, Wl, bl, xi, h0,
                       fcW1, fcW2, fcW3, Wpk,
                       esrc, rowp);

    float* hbuf[2] = {h0, h1};
    for (int l = 0; l < 3; ++l) {
        int do_h = (l < 2) ? 1 : 0;
        int lnext = do_h ? (l + 1) : l;
        hipLaunchKernelGGL(agg_fc_fused, dim3(NTILES), dim3(256), 0, stream,
                           WT, rowp, edst,
                           hbuf[l & 1], hbuf[(l + 1) & 1],
                           Wpk + (size_t)l * WPK_LAYER,
                           fcb1 + (size_t)l * 64, fcb2 + (size_t)l * 64,
                           fcb3 + (size_t)l * 64,
                           Wl + (size_t)lnext * 64 * 32,
                           bl + (size_t)lnext * 32,
                           do_h, xi);
    }
}